// Round 8
// baseline (636.905 us; speedup 1.0000x reference)
//
#include <hip/hip_runtime.h>
#include <hip/hip_fp16.h>
#include <math.h>

#define EPSF 1e-8f
#define BN_EPSF 1e-5f

typedef __attribute__((ext_vector_type(8))) short short8;   // 8 x bf16 (4 VGPRs)
typedef __attribute__((ext_vector_type(4))) float float4v;  // MFMA C/D

// f32 -> bf16 (round-to-nearest-even), bit pattern in a short
static __device__ __forceinline__ short f2bf(float f) {
    unsigned u = __float_as_uint(f);
    unsigned r = (u + 0x7FFFu + ((u >> 16) & 1u)) >> 16;
    return (short)r;
}

// f32 -> fp16 bits (v_cvt_f16_f32, RTN)
static __device__ __forceinline__ unsigned f2h(float f) {
    return (unsigned)__half_as_ushort(__float2half(f));
}

// Exact-GELU via A&S 7.1.26 minimax erf (|abs err| <= 1.5e-7) with HW rcp/exp2.
__device__ __forceinline__ float gelu_fast(float x) {
    const float z = fabsf(x) * 0.70710678118654752440f;
    const float t = __builtin_amdgcn_rcpf(1.0f + 0.3275911f * z);
    float p = 1.061405429f;
    p = p * t - 1.453152027f;
    p = p * t + 1.421413741f;
    p = p * t - 0.284496736f;
    p = p * t + 0.254829592f;
    p = p * t;
    const float e = __builtin_amdgcn_exp2f(z * z * -1.44269504088896340736f);
    float erfv = 1.0f - p * e;
    erfv = copysignf(erfv, x);
    return 0.5f * x * (1.0f + erfv);
}

// native packed-fp16 atomic add (HW instruction, no CAS)
static __device__ __forceinline__ void atomic_pk_add_f16(void* p, unsigned data) {
    const unsigned long long addr = (unsigned long long)p;
    asm volatile("global_atomic_pk_add_f16 %0, %1, off" :: "v"(addr), "v"(data) : "memory");
}

// ---------------------------------------------------------------------------
// Pack per-node data into [N][8]: {cx,cy,cz,nx, ny,nz,k0,k1} and zero the
// fp16 accumulator row + degree (replaces the separate memset dispatch).
// ---------------------------------------------------------------------------
__global__ __launch_bounds__(256) void pack_nodes_zero(
    const float* __restrict__ coords, const float* __restrict__ normals,
    const float* __restrict__ curv, float* __restrict__ pk,
    unsigned short* __restrict__ acch, float* __restrict__ deg, int N)
{
    const int n = blockIdx.x * blockDim.x + threadIdx.x;
    if (n < N) {
        float4 a, b;
        a.x = coords[3*n+0]; a.y = coords[3*n+1]; a.z = coords[3*n+2];
        a.w = normals[3*n+0];
        b.x = normals[3*n+1]; b.y = normals[3*n+2];
        b.z = curv[4*n+0];    b.w = curv[4*n+1];
        float4* o = (float4*)(pk + (size_t)n * 8);
        o[0] = a; o[1] = b;
        uint4* ab = (uint4*)(acch + (size_t)n * 16);
        ab[0] = make_uint4(0,0,0,0);
        ab[1] = make_uint4(0,0,0,0);
        deg[n] = 0.0f;
    }
}

// ---------------------------------------------------------------------------
// Edge kernel, MFMA v4. Same MLP as R6/R7. Scatter uses packed-fp16 HW
// atomics (fp16 = 11-bit significand: atomic-accum error ~8x below bf16,
// which failed at 0.29 vs 0.206; predicted ~0.1 total). Lane pair (m, m^1)
// swaps via shfl_xor(1); even lanes emit feats (m,m+1) to the row endpoint,
// odd lanes (m-1,m) to the col endpoint. Halves atomic bytes vs f32.
// BN stats remain f32-exact (taken from C-registers before fp16 pack).
// ---------------------------------------------------------------------------
__global__ __launch_bounds__(256, 5) void edge_kernel(
    const float* __restrict__ pk, const int* __restrict__ eidx,
    const float* __restrict__ W1, const float* __restrict__ b1,
    const float* __restrict__ W2, const float* __restrict__ b2,
    const float* __restrict__ W3, const float* __restrict__ b3,
    unsigned short* __restrict__ acch, float* __restrict__ deg,
    float* __restrict__ epartial, int E)
{
    __shared__ short w1t[64][32];        // W1^T, k-padded to 32 (k>=8 zero)
    __shared__ short w2t[32][64];        // W2^T
    __shared__ short w3t[16][32];        // W3^T
    __shared__ short ef_lds[4][64][8];   // per-wave edge features (bf16)
    __shared__ short h1_lds[4][16][72];  // per-wave h1 tile, row pad 64->72
    __shared__ short h2_lds[4][16][40];  // per-wave h2 tile, row pad 32->40
    __shared__ int   nidbuf[512];
    __shared__ float redbuf[4][32];

    const int t    = threadIdx.x;
    const int wv   = t >> 6;
    const int ln   = t & 63;
    const int qd   = ln >> 4;
    const int m    = ln & 15;
    const int base = blockIdx.x * 256;

    // ---- stage weights (bf16, transposed to B-operand row layout) ----
    for (int idx = t; idx < 64*32; idx += 256) {
        const int n = idx >> 5, k = idx & 31;
        w1t[n][k] = (k < 8) ? f2bf(W1[k*64 + n]) : (short)0;
    }
    for (int idx = t; idx < 32*64; idx += 256) {
        const int n = idx >> 6, k = idx & 63;
        w2t[n][k] = f2bf(W2[k*32 + n]);
    }
    for (int idx = t; idx < 16*32; idx += 256) {
        const int n = idx >> 5, k = idx & 31;
        w3t[n][k] = f2bf(W3[k*16 + n]);
    }

    // ---- per-lane geometry (one edge per lane) ----
    const int e = base + t;
    float ef[8];
    #pragma unroll
    for (int i = 0; i < 8; ++i) ef[i] = 0.0f;
    int r = -1, c = -1;
    if (e < E) {
        r = eidx[e];
        c = eidx[E + e];
        const float4 r0 = *(const float4*)(pk + (size_t)r * 8);
        const float4 r1 = *(const float4*)(pk + (size_t)r * 8 + 4);
        const float4 c0 = *(const float4*)(pk + (size_t)c * 8);
        const float4 c1 = *(const float4*)(pk + (size_t)c * 8 + 4);

        const float dx = c0.x - r0.x;
        const float dy = c0.y - r0.y;
        const float dz = c0.z - r0.z;
        const float nrx = r0.w, nry = r1.x, nrz = r1.y;
        const float ncx = c0.w, ncy = c1.x, ncz = c1.y;
        const float ndot = nrx*ncx + nry*ncy + nrz*ncz;
        const float dn = sqrtf(dx*dx + dy*dy + dz*dz) + EPSF;
        const float inv_dn = 1.0f / dn;
        float cr = (nrx*dx + nry*dy + nrz*dz) * inv_dn;
        float cc = (ncx*dx + ncy*dy + ncz*dz) * inv_dn;
        const float lo = -1.0f + EPSF, hi = 1.0f - EPSF;
        cr = fminf(fmaxf(cr, lo), hi);
        cc = fminf(fmaxf(cc, lo), hi);
        ef[0] = dx; ef[1] = dy; ef[2] = dz; ef[3] = ndot;
        ef[4] = cr; ef[5] = cc; ef[6] = c1.z - r1.z; ef[7] = c1.w - r1.w;

        unsafeAtomicAdd(&deg[r], 1.0f);
        unsafeAtomicAdd(&deg[c], 1.0f);
    }
    nidbuf[t]       = r;
    nidbuf[256 + t] = c;

    // pack ef -> bf16 LDS row (16B aligned store)
    {
        int p[4];
        #pragma unroll
        for (int i = 0; i < 4; ++i) {
            p[i] = ((unsigned short)f2bf(ef[2*i])) |
                   (((unsigned)(unsigned short)f2bf(ef[2*i+1])) << 16);
        }
        *(int4*)&ef_lds[wv][ln][0] = make_int4(p[0], p[1], p[2], p[3]);
    }

    __syncthreads();  // weights visible to all waves

    // ---- hoist weight fragments into registers (loop-invariant) ----
    short8 fw1[4], fw2[2][2], fw3;
    #pragma unroll
    for (int nt = 0; nt < 4; ++nt)
        fw1[nt] = *(const short8*)&w1t[nt*16 + m][qd*8];
    #pragma unroll
    for (int ks = 0; ks < 2; ++ks)
        #pragma unroll
        for (int nt = 0; nt < 2; ++nt)
            fw2[ks][nt] = *(const short8*)&w2t[nt*16 + m][ks*32 + qd*8];
    fw3 = *(const short8*)&w3t[m][qd*8];

    float bias1[4], bias2[2];
    #pragma unroll
    for (int nt = 0; nt < 4; ++nt) bias1[nt] = b1[nt*16 + m];
    #pragma unroll
    for (int nt = 0; nt < 2; ++nt) bias2[nt] = b2[nt*16 + m];
    const float bias3 = b3[m];

    const int pe   = m & 1;       // lane parity within feature dim
    const int half = m >> 1;      // fp16x2 word index in the acc row

    float ssum = 0.0f, qsum = 0.0f;

    for (int tl = 0; tl < 4; ++tl) {
        // ---- layer 1: A = ef tile (K=8 padded to 32) ----
        short8 a1 = {0,0,0,0,0,0,0,0};
        if (qd == 0) a1 = *(const short8*)&ef_lds[wv][tl*16 + m][0];
        float4v c1[4];
        #pragma unroll
        for (int nt = 0; nt < 4; ++nt) {
            c1[nt] = (float4v){bias1[nt], bias1[nt], bias1[nt], bias1[nt]};
            c1[nt] = __builtin_amdgcn_mfma_f32_16x16x32_bf16(a1, fw1[nt], c1[nt], 0, 0, 0);
        }
        #pragma unroll
        for (int nt = 0; nt < 4; ++nt)
            #pragma unroll
            for (int rg = 0; rg < 4; ++rg)
                h1_lds[wv][qd*4 + rg][nt*16 + m] = f2bf(gelu_fast(c1[nt][rg]));

        // ---- layer 2: K=64 (2 steps), N=32 (2 tiles) ----
        float4v c2[2];
        #pragma unroll
        for (int nt = 0; nt < 2; ++nt)
            c2[nt] = (float4v){bias2[nt], bias2[nt], bias2[nt], bias2[nt]};
        #pragma unroll
        for (int ks = 0; ks < 2; ++ks) {
            const short8 a2 = *(const short8*)&h1_lds[wv][m][ks*32 + qd*8];
            #pragma unroll
            for (int nt = 0; nt < 2; ++nt)
                c2[nt] = __builtin_amdgcn_mfma_f32_16x16x32_bf16(a2, fw2[ks][nt], c2[nt], 0, 0, 0);
        }
        #pragma unroll
        for (int nt = 0; nt < 2; ++nt)
            #pragma unroll
            for (int rg = 0; rg < 4; ++rg)
                h2_lds[wv][qd*4 + rg][nt*16 + m] = f2bf(gelu_fast(c2[nt][rg]));

        // ---- layer 3: K=32, N=16 ----
        const short8 a3 = *(const short8*)&h2_lds[wv][m][qd*8];
        float4v c3 = (float4v){bias3, bias3, bias3, bias3};
        c3 = __builtin_amdgcn_mfma_f32_16x16x32_bf16(a3, fw3, c3, 0, 0, 0);

        // ---- packed-fp16 scatter + f32 BN stats ----
        const int ebase = wv*64 + tl*16 + qd*4;
        #pragma unroll
        for (int rg = 0; rg < 4; ++rg) {
            const int ebl = ebase + rg;
            const int nr  = nidbuf[ebl];          // uniform across quad
            const int nc  = nidbuf[256 + ebl];
            float v = c3[rg];
            if (nr < 0) v = 0.0f;                 // tail edge
            ssum += v;
            qsum += v * v;
            const float vp = __shfl_xor(v, 1);    // partner feature value
            if (nr >= 0) {
                const int tgt = pe ? nc : nr;
                const unsigned lo = f2h(pe ? vp : v);
                const unsigned hi = f2h(pe ? v : vp);
                atomic_pk_add_f16(acch + (size_t)tgt * 16 + half * 2,
                                  lo | (hi << 16));
            }
        }
    }

    // BN stats: lane holds (feat=m) partial over its 16 edges; reduce quads
    ssum += __shfl_xor(ssum, 16); ssum += __shfl_xor(ssum, 32);
    qsum += __shfl_xor(qsum, 16); qsum += __shfl_xor(qsum, 32);
    if (qd == 0) redbuf[wv][m]      = ssum;
    if (qd == 1) redbuf[wv][16 + m] = qsum;
    __syncthreads();

    if (t < 32) {
        epartial[(size_t)blockIdx.x * 32 + t] =
            redbuf[0][t] + redbuf[1][t] + redbuf[2][t] + redbuf[3][t];
    }
}

// ---------------------------------------------------------------------------
// Fused: sum per-block partials [nblk][32] -> BN affine coefficients.
// One block of 256; coalesced column sums; out = a*x + c form.
// ---------------------------------------------------------------------------
__global__ __launch_bounds__(256) void reduce_finalize(
    const float* __restrict__ p, int nblk,
    const float* __restrict__ g, const float* __restrict__ b,
    float cnt_inv, float* __restrict__ coef)
{
    __shared__ float sb[8][32];
    const int t  = threadIdx.x;
    const int k  = t & 31;
    const int ch = t >> 5;
    float s = 0.0f;
    for (int i = ch; i < nblk; i += 8) s += p[(size_t)i * 32 + k];
    sb[ch][k] = s;
    __syncthreads();
    if (t < 32) {
        float tot = 0.0f;
        #pragma unroll
        for (int j = 0; j < 8; ++j) tot += sb[j][k];
        sb[0][k] = tot;
    }
    __syncthreads();
    if (t < 16) {
        const float mean = sb[0][t] * cnt_inv;
        const float var  = sb[0][16 + t] * cnt_inv - mean * mean;
        const float inv  = rsqrtf(var + BN_EPSF);
        const float a    = g[t] * inv;
        coef[t]      = a;
        coef[16 + t] = b[t] - mean * a;
    }
}

// ---------------------------------------------------------------------------
// Node kernel: decode fp16 acc, edge-BN affine + degree norm, 16x16
// projection, store y to d_out, block-reduced node-BN partials.
// ---------------------------------------------------------------------------
__global__ __launch_bounds__(256) void node_kernel(
    const unsigned short* __restrict__ acch, const float* __restrict__ deg,
    const float* __restrict__ ecoef,
    const float* __restrict__ Wp, const float* __restrict__ bp,
    float* __restrict__ y, float* __restrict__ npartial, int N)
{
    __shared__ float redbuf[4][32];
    const int t = threadIdx.x;
    const int n = blockIdx.x * 256 + t;

    float yv[16];
    #pragma unroll
    for (int j = 0; j < 16; ++j) yv[j] = 0.0f;

    if (n < N) {
        const float d   = deg[n];
        const float inv = 1.0f / fmaxf(d, 1.0f);
        const uint4* arow = (const uint4*)(acch + (size_t)n * 16);
        const uint4 u0 = arow[0];
        const uint4 u1 = arow[1];
        unsigned w[8] = {u0.x, u0.y, u0.z, u0.w, u1.x, u1.y, u1.z, u1.w};
        float x[16];
        #pragma unroll
        for (int q = 0; q < 8; ++q) {
            x[2*q]   = __half2float(__ushort_as_half((unsigned short)(w[q] & 0xFFFFu)));
            x[2*q+1] = __half2float(__ushort_as_half((unsigned short)(w[q] >> 16)));
        }
        #pragma unroll
        for (int j = 0; j < 16; ++j)
            x[j] = (ecoef[j] * x[j] + ecoef[16 + j] * d) * inv;

        #pragma unroll
        for (int j = 0; j < 16; ++j) yv[j] = bp[j];
        #pragma unroll
        for (int i = 0; i < 16; ++i) {
            const float v = x[i];
            #pragma unroll
            for (int j = 0; j < 16; ++j) yv[j] += v * Wp[i*16 + j];
        }
        float4* yrow = (float4*)(y + (size_t)n * 16);
        #pragma unroll
        for (int q = 0; q < 4; ++q) {
            float4 o;
            o.x = yv[4*q+0]; o.y = yv[4*q+1]; o.z = yv[4*q+2]; o.w = yv[4*q+3];
            yrow[q] = o;
        }
    }

    const int wave = t >> 6;
    #pragma unroll
    for (int j = 0; j < 16; ++j) {
        float s = yv[j];
        float q = yv[j] * yv[j];
        #pragma unroll
        for (int o = 32; o > 0; o >>= 1) {
            s += __shfl_xor(s, o);
            q += __shfl_xor(q, o);
        }
        if ((t & 63) == 0) {
            redbuf[wave][j]      = s;
            redbuf[wave][16 + j] = q;
        }
    }
    __syncthreads();
    if (t < 32) {
        npartial[(size_t)blockIdx.x * 32 + t] =
            redbuf[0][t] + redbuf[1][t] + redbuf[2][t] + redbuf[3][t];
    }
}

// ---------------------------------------------------------------------------
// Epilogue: out = out * a2 + c2 (node BN affine), in place, float4.
// ---------------------------------------------------------------------------
__global__ __launch_bounds__(256) void final_kernel(
    float* __restrict__ out, const float* __restrict__ ncoef, int total)
{
    const int i = (blockIdx.x * blockDim.x + threadIdx.x) * 4;
    if (i < total) {
        const float4 v = *(const float4*)(out + i);
        const int j = i & 15;
        const float4 a = *(const float4*)(ncoef + j);
        const float4 c = *(const float4*)(ncoef + 16 + j);
        float4 o;
        o.x = v.x * a.x + c.x;
        o.y = v.y * a.y + c.y;
        o.z = v.z * a.z + c.z;
        o.w = v.w * a.w + c.w;
        *(float4*)(out + i) = o;
    }
}

extern "C" void kernel_launch(void* const* d_in, const int* in_sizes, int n_in,
                              void* d_out, int out_size, void* d_ws, size_t ws_size,
                              hipStream_t stream) {
    const float* coords = (const float*)d_in[0];
    const float* normals = (const float*)d_in[1];
    const float* curv = (const float*)d_in[2];
    const int*   eidx = (const int*)d_in[3];
    const float* W1 = (const float*)d_in[4];
    const float* b1 = (const float*)d_in[5];
    const float* W2 = (const float*)d_in[6];
    const float* b2 = (const float*)d_in[7];
    const float* W3 = (const float*)d_in[8];
    const float* b3 = (const float*)d_in[9];
    const float* Wp = (const float*)d_in[10];
    const float* bp = (const float*)d_in[11];
    const float* bn_edge_g = (const float*)d_in[12];
    const float* bn_edge_b = (const float*)d_in[13];
    const float* bn_node_g = (const float*)d_in[14];
    const float* bn_node_b = (const float*)d_in[15];

    const int N = in_sizes[0] / 3;
    const int E = in_sizes[3] / 2;

    const int eblocks = (E + 255) / 256;
    const int nblocks = (N + 255) / 256;

    // workspace layout:
    float* ws = (float*)d_ws;
    unsigned short* acch = (unsigned short*)ws;          // N*16 fp16 (= N*8 floats)
    float* deg      = ws + (size_t)N * 8;                // N
    float* ecoef    = deg + N;                           // 32
    float* ncoef    = ecoef + 32;                        // 32
    float* epartial = ncoef + 32;                        // eblocks*32
    float* npartial = epartial + (size_t)eblocks * 32;   // nblocks*32
    float* pk       = npartial + (size_t)nblocks * 32;   // N*8

    pack_nodes_zero<<<nblocks, 256, 0, stream>>>(coords, normals, curv, pk, acch, deg, N);

    edge_kernel<<<eblocks, 256, 0, stream>>>(
        pk, eidx, W1, b1, W2, b2, W3, b3, acch, deg, epartial, E);

    reduce_finalize<<<1, 256, 0, stream>>>(epartial, eblocks, bn_edge_g, bn_edge_b,
                                           1.0f / (float)E, ecoef);

    node_kernel<<<nblocks, 256, 0, stream>>>(
        acch, deg, ecoef, Wp, bp, (float*)d_out, npartial, N);

    reduce_finalize<<<1, 256, 0, stream>>>(npartial, nblocks, bn_node_g, bn_node_b,
                                           1.0f / (float)N, ncoef);

    const int total = N * 16;
    final_kernel<<<(total / 4 + 255) / 256, 256, 0, stream>>>((float*)d_out, ncoef, total);
}

// Round 9
// 455.929 us; speedup vs baseline: 1.3969x; 1.3969x over previous
//
#include <hip/hip_runtime.h>
#include <hip/hip_fp16.h>
#include <math.h>

#define EPSF 1e-8f
#define BN_EPSF 1e-5f

typedef __attribute__((ext_vector_type(8))) short short8;   // 8 x bf16 (4 VGPRs)
typedef __attribute__((ext_vector_type(4))) float float4v;  // MFMA C/D

// f32 -> bf16 (round-to-nearest-even), bit pattern in a short
static __device__ __forceinline__ short f2bf(float f) {
    unsigned u = __float_as_uint(f);
    unsigned r = (u + 0x7FFFu + ((u >> 16) & 1u)) >> 16;
    return (short)r;
}

// f32 -> fp16 bits (v_cvt_f16_f32, RTN)
static __device__ __forceinline__ unsigned f2h(float f) {
    return (unsigned)__half_as_ushort(__float2half(f));
}

// Exact-GELU via A&S 7.1.26 minimax erf (|abs err| <= 1.5e-7) with HW rcp/exp2.
__device__ __forceinline__ float gelu_fast(float x) {
    const float z = fabsf(x) * 0.70710678118654752440f;
    const float t = __builtin_amdgcn_rcpf(1.0f + 0.3275911f * z);
    float p = 1.061405429f;
    p = p * t - 1.453152027f;
    p = p * t + 1.421413741f;
    p = p * t - 0.284496736f;
    p = p * t + 0.254829592f;
    p = p * t;
    const float e = __builtin_amdgcn_exp2f(z * z * -1.44269504088896340736f);
    float erfv = 1.0f - p * e;
    erfv = copysignf(erfv, x);
    return 0.5f * x * (1.0f + erfv);
}

// native packed-fp16 atomic add (HW instruction, no CAS)
static __device__ __forceinline__ void atomic_pk_add_f16(void* p, unsigned data) {
    const unsigned long long addr = (unsigned long long)p;
    asm volatile("global_atomic_pk_add_f16 %0, %1, off" :: "v"(addr), "v"(data) : "memory");
}

// ---------------------------------------------------------------------------
// Pack per-node data into [N][8]: {cx,cy,cz,nx, ny,nz,k0,k1} and zero the
// node accumulator line (64B: 16 fp16 feats + fp16 deg + pad).
// ---------------------------------------------------------------------------
__global__ __launch_bounds__(256) void pack_nodes_zero(
    const float* __restrict__ coords, const float* __restrict__ normals,
    const float* __restrict__ curv, float* __restrict__ pk,
    unsigned short* __restrict__ acch, int N)
{
    const int n = blockIdx.x * blockDim.x + threadIdx.x;
    if (n < N) {
        float4 a, b;
        a.x = coords[3*n+0]; a.y = coords[3*n+1]; a.z = coords[3*n+2];
        a.w = normals[3*n+0];
        b.x = normals[3*n+1]; b.y = normals[3*n+2];
        b.z = curv[4*n+0];    b.w = curv[4*n+1];
        float4* o = (float4*)(pk + (size_t)n * 8);
        o[0] = a; o[1] = b;
        uint4* ab = (uint4*)(acch + (size_t)n * 32);
        const uint4 z = make_uint4(0,0,0,0);
        ab[0] = z; ab[1] = z; ab[2] = z; ab[3] = z;
    }
}

// ---------------------------------------------------------------------------
// Edge kernel, MFMA v5. Same MLP as R6-R8. Scatter: packed-fp16 HW atomics
// into a 64B-per-node accumulator LINE holding feats[0:16] (halves 0-15) AND
// degree (half 16). Lanes 0/1 of each quad add {1.0,0} to half 16 of the
// row/col line the quad is already touching -> deg rides in the SAME line
// event. Line events per edge: 4 -> 2 (R8 evidence: cost is per 64B line
// event, not per byte -- 64B vs 32B payloads timed identically).
// BN stats stay f32-exact via per-block partials (parallel reduce after).
// ---------------------------------------------------------------------------
__global__ __launch_bounds__(256, 5) void edge_kernel(
    const float* __restrict__ pk, const int* __restrict__ eidx,
    const float* __restrict__ W1, const float* __restrict__ b1,
    const float* __restrict__ W2, const float* __restrict__ b2,
    const float* __restrict__ W3, const float* __restrict__ b3,
    unsigned short* __restrict__ acch,
    float* __restrict__ epartial, int E)
{
    __shared__ short w1t[64][32];        // W1^T, k-padded to 32 (k>=8 zero)
    __shared__ short w2t[32][64];        // W2^T
    __shared__ short w3t[16][32];        // W3^T
    __shared__ short ef_lds[4][64][8];   // per-wave edge features (bf16)
    __shared__ short h1_lds[4][16][72];  // per-wave h1 tile, row pad 64->72
    __shared__ short h2_lds[4][16][40];  // per-wave h2 tile, row pad 32->40
    __shared__ int   nidbuf[512];
    __shared__ float redbuf[4][32];

    const int t    = threadIdx.x;
    const int wv   = t >> 6;
    const int ln   = t & 63;
    const int qd   = ln >> 4;
    const int m    = ln & 15;
    const int base = blockIdx.x * 256;

    // ---- stage weights (bf16, transposed to B-operand row layout) ----
    for (int idx = t; idx < 64*32; idx += 256) {
        const int n = idx >> 5, k = idx & 31;
        w1t[n][k] = (k < 8) ? f2bf(W1[k*64 + n]) : (short)0;
    }
    for (int idx = t; idx < 32*64; idx += 256) {
        const int n = idx >> 6, k = idx & 63;
        w2t[n][k] = f2bf(W2[k*32 + n]);
    }
    for (int idx = t; idx < 16*32; idx += 256) {
        const int n = idx >> 5, k = idx & 31;
        w3t[n][k] = f2bf(W3[k*16 + n]);
    }

    // ---- per-lane geometry (one edge per lane) ----
    const int e = base + t;
    float ef[8];
    #pragma unroll
    for (int i = 0; i < 8; ++i) ef[i] = 0.0f;
    int r = -1, c = -1;
    if (e < E) {
        r = eidx[e];
        c = eidx[E + e];
        const float4 r0 = *(const float4*)(pk + (size_t)r * 8);
        const float4 r1 = *(const float4*)(pk + (size_t)r * 8 + 4);
        const float4 c0 = *(const float4*)(pk + (size_t)c * 8);
        const float4 c1 = *(const float4*)(pk + (size_t)c * 8 + 4);

        const float dx = c0.x - r0.x;
        const float dy = c0.y - r0.y;
        const float dz = c0.z - r0.z;
        const float nrx = r0.w, nry = r1.x, nrz = r1.y;
        const float ncx = c0.w, ncy = c1.x, ncz = c1.y;
        const float ndot = nrx*ncx + nry*ncy + nrz*ncz;
        const float dn = sqrtf(dx*dx + dy*dy + dz*dz) + EPSF;
        const float inv_dn = 1.0f / dn;
        float cr = (nrx*dx + nry*dy + nrz*dz) * inv_dn;
        float cc = (ncx*dx + ncy*dy + ncz*dz) * inv_dn;
        const float lo = -1.0f + EPSF, hi = 1.0f - EPSF;
        cr = fminf(fmaxf(cr, lo), hi);
        cc = fminf(fmaxf(cc, lo), hi);
        ef[0] = dx; ef[1] = dy; ef[2] = dz; ef[3] = ndot;
        ef[4] = cr; ef[5] = cc; ef[6] = c1.z - r1.z; ef[7] = c1.w - r1.w;
    }
    nidbuf[t]       = r;
    nidbuf[256 + t] = c;

    // pack ef -> bf16 LDS row (16B aligned store)
    {
        int p[4];
        #pragma unroll
        for (int i = 0; i < 4; ++i) {
            p[i] = ((unsigned short)f2bf(ef[2*i])) |
                   (((unsigned)(unsigned short)f2bf(ef[2*i+1])) << 16);
        }
        *(int4*)&ef_lds[wv][ln][0] = make_int4(p[0], p[1], p[2], p[3]);
    }

    __syncthreads();  // weights visible to all waves

    // ---- hoist weight fragments into registers (loop-invariant) ----
    short8 fw1[4], fw2[2][2], fw3;
    #pragma unroll
    for (int nt = 0; nt < 4; ++nt)
        fw1[nt] = *(const short8*)&w1t[nt*16 + m][qd*8];
    #pragma unroll
    for (int ks = 0; ks < 2; ++ks)
        #pragma unroll
        for (int nt = 0; nt < 2; ++nt)
            fw2[ks][nt] = *(const short8*)&w2t[nt*16 + m][ks*32 + qd*8];
    fw3 = *(const short8*)&w3t[m][qd*8];

    float bias1[4], bias2[2];
    #pragma unroll
    for (int nt = 0; nt < 4; ++nt) bias1[nt] = b1[nt*16 + m];
    #pragma unroll
    for (int nt = 0; nt < 2; ++nt) bias2[nt] = b2[nt*16 + m];
    const float bias3 = b3[m];

    const int pe   = m & 1;       // lane parity within feature dim
    const int half = m >> 1;      // fp16x2 word index in the acc row

    float ssum = 0.0f, qsum = 0.0f;

    for (int tl = 0; tl < 4; ++tl) {
        // ---- layer 1: A = ef tile (K=8 padded to 32) ----
        short8 a1 = {0,0,0,0,0,0,0,0};
        if (qd == 0) a1 = *(const short8*)&ef_lds[wv][tl*16 + m][0];
        float4v c1[4];
        #pragma unroll
        for (int nt = 0; nt < 4; ++nt) {
            c1[nt] = (float4v){bias1[nt], bias1[nt], bias1[nt], bias1[nt]};
            c1[nt] = __builtin_amdgcn_mfma_f32_16x16x32_bf16(a1, fw1[nt], c1[nt], 0, 0, 0);
        }
        #pragma unroll
        for (int nt = 0; nt < 4; ++nt)
            #pragma unroll
            for (int rg = 0; rg < 4; ++rg)
                h1_lds[wv][qd*4 + rg][nt*16 + m] = f2bf(gelu_fast(c1[nt][rg]));

        // ---- layer 2: K=64 (2 steps), N=32 (2 tiles) ----
        float4v c2[2];
        #pragma unroll
        for (int nt = 0; nt < 2; ++nt)
            c2[nt] = (float4v){bias2[nt], bias2[nt], bias2[nt], bias2[nt]};
        #pragma unroll
        for (int ks = 0; ks < 2; ++ks) {
            const short8 a2 = *(const short8*)&h1_lds[wv][m][ks*32 + qd*8];
            #pragma unroll
            for (int nt = 0; nt < 2; ++nt)
                c2[nt] = __builtin_amdgcn_mfma_f32_16x16x32_bf16(a2, fw2[ks][nt], c2[nt], 0, 0, 0);
        }
        #pragma unroll
        for (int nt = 0; nt < 2; ++nt)
            #pragma unroll
            for (int rg = 0; rg < 4; ++rg)
                h2_lds[wv][qd*4 + rg][nt*16 + m] = f2bf(gelu_fast(c2[nt][rg]));

        // ---- layer 3: K=32, N=16 ----
        const short8 a3 = *(const short8*)&h2_lds[wv][m][qd*8];
        float4v c3 = (float4v){bias3, bias3, bias3, bias3};
        c3 = __builtin_amdgcn_mfma_f32_16x16x32_bf16(a3, fw3, c3, 0, 0, 0);

        // ---- packed-fp16 scatter (feats + deg in ONE 64B line) + stats ----
        const int ebase = wv*64 + tl*16 + qd*4;
        #pragma unroll
        for (int rg = 0; rg < 4; ++rg) {
            const int ebl = ebase + rg;
            const int nr  = nidbuf[ebl];          // uniform across quad
            const int nc  = nidbuf[256 + ebl];
            float v = c3[rg];
            if (nr < 0) v = 0.0f;                 // tail edge
            ssum += v;
            qsum += v * v;
            const float vp = __shfl_xor(v, 1);    // partner feature value
            if (nr >= 0) {
                const int tgt = pe ? nc : nr;     // lane0 -> row, lane1 -> col
                const unsigned lo = f2h(pe ? vp : v);
                const unsigned hi = f2h(pe ? v : vp);
                unsigned short* line = acch + (size_t)tgt * 32;
                atomic_pk_add_f16(line + half * 2, lo | (hi << 16));
                if (m < 2) atomic_pk_add_f16(line + 16, 0x3C00u);  // deg += 1.0
            }
        }
    }

    // BN stats: lane holds (feat=m) partial over its 16 edges; reduce quads
    ssum += __shfl_xor(ssum, 16); ssum += __shfl_xor(ssum, 32);
    qsum += __shfl_xor(qsum, 16); qsum += __shfl_xor(qsum, 32);
    if (qd == 0) redbuf[wv][m]      = ssum;
    if (qd == 1) redbuf[wv][16 + m] = qsum;
    __syncthreads();

    if (t < 32) {
        epartial[(size_t)blockIdx.x * 32 + t] =
            redbuf[0][t] + redbuf[1][t] + redbuf[2][t] + redbuf[3][t];
    }
}

// ---------------------------------------------------------------------------
// Sum per-block partials [nblk][32] -> stats[32]. One block per stat index.
// ---------------------------------------------------------------------------
__global__ __launch_bounds__(256) void reduce_partials(
    const float* __restrict__ p, int nblk, float* __restrict__ stats)
{
    const int k = blockIdx.x;
    float s = 0.0f;
    for (int i = threadIdx.x; i < nblk; i += blockDim.x) s += p[(size_t)i * 32 + k];
    #pragma unroll
    for (int o = 32; o > 0; o >>= 1) s += __shfl_xor(s, o);
    __shared__ float w[4];
    if ((threadIdx.x & 63) == 0) w[threadIdx.x >> 6] = s;
    __syncthreads();
    if (threadIdx.x == 0) stats[k] = w[0] + w[1] + w[2] + w[3];
}

// ---------------------------------------------------------------------------
// BN finalize -> affine coefficients: out = a*x + c
// ---------------------------------------------------------------------------
__global__ void finalize_bn(const float* __restrict__ stats,
                            const float* __restrict__ g, const float* __restrict__ b,
                            float cnt_inv, float* __restrict__ coef)
{
    const int j = threadIdx.x;
    if (j < 16) {
        const float mean = stats[j] * cnt_inv;
        const float var  = stats[16 + j] * cnt_inv - mean * mean;
        const float inv  = rsqrtf(var + BN_EPSF);
        const float a    = g[j] * inv;
        coef[j]      = a;
        coef[16 + j] = b[j] - mean * a;
    }
}

// ---------------------------------------------------------------------------
// Node kernel: decode fp16 acc line (feats + deg), edge-BN affine + degree
// norm, 16x16 projection, store y to d_out, block-reduced node-BN partials.
// ---------------------------------------------------------------------------
__global__ __launch_bounds__(256) void node_kernel(
    const unsigned short* __restrict__ acch,
    const float* __restrict__ ecoef,
    const float* __restrict__ Wp, const float* __restrict__ bp,
    float* __restrict__ y, float* __restrict__ npartial, int N)
{
    __shared__ float redbuf[4][32];
    const int t = threadIdx.x;
    const int n = blockIdx.x * 256 + t;

    float yv[16];
    #pragma unroll
    for (int j = 0; j < 16; ++j) yv[j] = 0.0f;

    if (n < N) {
        const unsigned short* row = acch + (size_t)n * 32;
        const uint4 u0 = *(const uint4*)row;
        const uint4 u1 = *(const uint4*)(row + 8);
        const float d  = __half2float(__ushort_as_half(row[16]));
        const float inv = 1.0f / fmaxf(d, 1.0f);
        unsigned w[8] = {u0.x, u0.y, u0.z, u0.w, u1.x, u1.y, u1.z, u1.w};
        float x[16];
        #pragma unroll
        for (int q = 0; q < 8; ++q) {
            x[2*q]   = __half2float(__ushort_as_half((unsigned short)(w[q] & 0xFFFFu)));
            x[2*q+1] = __half2float(__ushort_as_half((unsigned short)(w[q] >> 16)));
        }
        #pragma unroll
        for (int j = 0; j < 16; ++j)
            x[j] = (ecoef[j] * x[j] + ecoef[16 + j] * d) * inv;

        #pragma unroll
        for (int j = 0; j < 16; ++j) yv[j] = bp[j];
        #pragma unroll
        for (int i = 0; i < 16; ++i) {
            const float v = x[i];
            #pragma unroll
            for (int j = 0; j < 16; ++j) yv[j] += v * Wp[i*16 + j];
        }
        float4* yrow = (float4*)(y + (size_t)n * 16);
        #pragma unroll
        for (int q = 0; q < 4; ++q) {
            float4 o;
            o.x = yv[4*q+0]; o.y = yv[4*q+1]; o.z = yv[4*q+2]; o.w = yv[4*q+3];
            yrow[q] = o;
        }
    }

    const int wave = t >> 6;
    #pragma unroll
    for (int j = 0; j < 16; ++j) {
        float s = yv[j];
        float q = yv[j] * yv[j];
        #pragma unroll
        for (int o = 32; o > 0; o >>= 1) {
            s += __shfl_xor(s, o);
            q += __shfl_xor(q, o);
        }
        if ((t & 63) == 0) {
            redbuf[wave][j]      = s;
            redbuf[wave][16 + j] = q;
        }
    }
    __syncthreads();
    if (t < 32) {
        npartial[(size_t)blockIdx.x * 32 + t] =
            redbuf[0][t] + redbuf[1][t] + redbuf[2][t] + redbuf[3][t];
    }
}

// ---------------------------------------------------------------------------
// Epilogue: out = out * a2 + c2 (node BN affine), in place, float4.
// ---------------------------------------------------------------------------
__global__ __launch_bounds__(256) void final_kernel(
    float* __restrict__ out, const float* __restrict__ ncoef, int total)
{
    const int i = (blockIdx.x * blockDim.x + threadIdx.x) * 4;
    if (i < total) {
        const float4 v = *(const float4*)(out + i);
        const int j = i & 15;
        const float4 a = *(const float4*)(ncoef + j);
        const float4 c = *(const float4*)(ncoef + 16 + j);
        float4 o;
        o.x = v.x * a.x + c.x;
        o.y = v.y * a.y + c.y;
        o.z = v.z * a.z + c.z;
        o.w = v.w * a.w + c.w;
        *(float4*)(out + i) = o;
    }
}

extern "C" void kernel_launch(void* const* d_in, const int* in_sizes, int n_in,
                              void* d_out, int out_size, void* d_ws, size_t ws_size,
                              hipStream_t stream) {
    const float* coords = (const float*)d_in[0];
    const float* normals = (const float*)d_in[1];
    const float* curv = (const float*)d_in[2];
    const int*   eidx = (const int*)d_in[3];
    const float* W1 = (const float*)d_in[4];
    const float* b1 = (const float*)d_in[5];
    const float* W2 = (const float*)d_in[6];
    const float* b2 = (const float*)d_in[7];
    const float* W3 = (const float*)d_in[8];
    const float* b3 = (const float*)d_in[9];
    const float* Wp = (const float*)d_in[10];
    const float* bp = (const float*)d_in[11];
    const float* bn_edge_g = (const float*)d_in[12];
    const float* bn_edge_b = (const float*)d_in[13];
    const float* bn_node_g = (const float*)d_in[14];
    const float* bn_node_b = (const float*)d_in[15];

    const int N = in_sizes[0] / 3;
    const int E = in_sizes[3] / 2;

    const int eblocks = (E + 255) / 256;
    const int nblocks = (N + 255) / 256;

    // workspace layout:
    float* ws = (float*)d_ws;
    unsigned short* acch = (unsigned short*)ws;          // N lines x 32 halves (64B)
    float* ecoef    = ws + (size_t)N * 16;               // 32
    float* ncoef    = ecoef + 32;                        // 32
    float* estats   = ncoef + 32;                        // 32
    float* nstats   = estats + 32;                       // 32
    float* epartial = nstats + 32;                       // eblocks*32
    float* npartial = epartial + (size_t)eblocks * 32;   // nblocks*32
    float* pk       = npartial + (size_t)nblocks * 32;   // N*8

    pack_nodes_zero<<<nblocks, 256, 0, stream>>>(coords, normals, curv, pk, acch, N);

    edge_kernel<<<eblocks, 256, 0, stream>>>(
        pk, eidx, W1, b1, W2, b2, W3, b3, acch, epartial, E);

    reduce_partials<<<32, 256, 0, stream>>>(epartial, eblocks, estats);
    finalize_bn<<<1, 64, 0, stream>>>(estats, bn_edge_g, bn_edge_b, 1.0f / (float)E, ecoef);

    node_kernel<<<nblocks, 256, 0, stream>>>(
        acch, ecoef, Wp, bp, (float*)d_out, npartial, N);

    reduce_partials<<<32, 256, 0, stream>>>(npartial, nblocks, nstats);
    finalize_bn<<<1, 64, 0, stream>>>(nstats, bn_node_g, bn_node_b, 1.0f / (float)N, ncoef);

    const int total = N * 16;
    final_kernel<<<(total / 4 + 255) / 256, 256, 0, stream>>>((float*)d_out, ncoef, total);
}

// Round 10
// 332.262 us; speedup vs baseline: 1.9169x; 1.3722x over previous
//
#include <hip/hip_runtime.h>
#include <hip/hip_fp16.h>
#include <math.h>

#define EPSF 1e-8f
#define BN_EPSF 1e-5f

typedef __attribute__((ext_vector_type(8))) short short8;   // 8 x bf16 (4 VGPRs)
typedef __attribute__((ext_vector_type(4))) float float4v;  // MFMA C/D

// f32 -> bf16 (round-to-nearest-even), bit pattern in a short
static __device__ __forceinline__ short f2bf(float f) {
    unsigned u = __float_as_uint(f);
    unsigned r = (u + 0x7FFFu + ((u >> 16) & 1u)) >> 16;
    return (short)r;
}

// f32 -> fp16 bits (v_cvt_f16_f32, RTN)
static __device__ __forceinline__ unsigned short f2h(float f) {
    return __half_as_ushort(__float2half(f));
}

// Exact-GELU via A&S 7.1.26 minimax erf (|abs err| <= 1.5e-7) with HW rcp/exp2.
__device__ __forceinline__ float gelu_fast(float x) {
    const float z = fabsf(x) * 0.70710678118654752440f;
    const float t = __builtin_amdgcn_rcpf(1.0f + 0.3275911f * z);
    float p = 1.061405429f;
    p = p * t - 1.453152027f;
    p = p * t + 1.421413741f;
    p = p * t - 0.284496736f;
    p = p * t + 0.254829592f;
    p = p * t;
    const float e = __builtin_amdgcn_exp2f(z * z * -1.44269504088896340736f);
    float erfv = 1.0f - p * e;
    erfv = copysignf(erfv, x);
    return 0.5f * x * (1.0f + erfv);
}

// native packed-fp16 atomic add (HW instruction, no CAS)
static __device__ __forceinline__ void atomic_pk_add_f16(void* p, unsigned data) {
    const unsigned long long addr = (unsigned long long)p;
    asm volatile("global_atomic_pk_add_f16 %0, %1, off" :: "v"(addr), "v"(data) : "memory");
}

// ---------------------------------------------------------------------------
// Pack per-node data into [N][8]: {cx,cy,cz,nx, ny,nz,k0,k1} and zero the
// node accumulator line (64B: 16 fp16 feats + fp16 deg + pad).
// ---------------------------------------------------------------------------
__global__ __launch_bounds__(256) void pack_nodes_zero(
    const float* __restrict__ coords, const float* __restrict__ normals,
    const float* __restrict__ curv, float* __restrict__ pk,
    unsigned short* __restrict__ acch, int N)
{
    const int n = blockIdx.x * blockDim.x + threadIdx.x;
    if (n < N) {
        float4 a, b;
        a.x = coords[3*n+0]; a.y = coords[3*n+1]; a.z = coords[3*n+2];
        a.w = normals[3*n+0];
        b.x = normals[3*n+1]; b.y = normals[3*n+2];
        b.z = curv[4*n+0];    b.w = curv[4*n+1];
        float4* o = (float4*)(pk + (size_t)n * 8);
        o[0] = a; o[1] = b;
        uint4* ab = (uint4*)(acch + (size_t)n * 32);
        const uint4 z = make_uint4(0,0,0,0);
        ab[0] = z; ab[1] = z; ab[2] = z; ab[3] = z;
    }
}

// ---------------------------------------------------------------------------
// Edge kernel, MFMA v6. Same MLP as R6-R9. Scatter: 9-LANE MARSHALLED
// packed-fp16 atomics -- each 64B node-line update (16 feats + deg) is one
// wave-instruction-line EVENT: roles 0-7 carry feat pairs, role 8 carries
// {1.0h,0} into halves 16-17. 7 line-jobs per instruction (63 lanes).
// Events per edge: 4 (R6-R9, all ~331 us) -> 2, the push-scatter minimum.
// Evidence: R6/R8/R9 held 6.4M events at ~19.3 G events/s across payload
// widths and instruction counts -- cost is per instruction-per-line event.
// ---------------------------------------------------------------------------
__global__ __launch_bounds__(256, 4) void edge_kernel(
    const float* __restrict__ pk, const int* __restrict__ eidx,
    const float* __restrict__ W1, const float* __restrict__ b1,
    const float* __restrict__ W2, const float* __restrict__ b2,
    const float* __restrict__ W3, const float* __restrict__ b3,
    unsigned short* __restrict__ acch,
    float* __restrict__ epartial, int E)
{
    __shared__ short w1t[64][32];            // W1^T, k-padded to 32 (k>=8 zero)
    __shared__ short w2t[32][64];            // W2^T
    __shared__ short w3t[16][32];            // W3^T
    __shared__ short ef_lds[4][64][8];       // per-wave edge features (bf16)
    __shared__ short h1_lds[4][16][72];      // per-wave h1 tile, row pad 64->72
    __shared__ short h2_lds[4][16][40];      // per-wave h2 tile, row pad 32->40
    __shared__ unsigned short hbuf16[256][18]; // fp16 h3 staging (36B rows)
    __shared__ int   nidbuf[512];
    __shared__ float redbuf[4][32];

    const int t    = threadIdx.x;
    const int wv   = t >> 6;
    const int ln   = t & 63;
    const int qd   = ln >> 4;
    const int m    = ln & 15;
    const int base = blockIdx.x * 256;

    // ---- stage weights (bf16, transposed to B-operand row layout) ----
    for (int idx = t; idx < 64*32; idx += 256) {
        const int n = idx >> 5, k = idx & 31;
        w1t[n][k] = (k < 8) ? f2bf(W1[k*64 + n]) : (short)0;
    }
    for (int idx = t; idx < 32*64; idx += 256) {
        const int n = idx >> 6, k = idx & 63;
        w2t[n][k] = f2bf(W2[k*32 + n]);
    }
    for (int idx = t; idx < 16*32; idx += 256) {
        const int n = idx >> 5, k = idx & 31;
        w3t[n][k] = f2bf(W3[k*16 + n]);
    }

    // ---- per-lane geometry (one edge per lane) ----
    const int e = base + t;
    float ef[8];
    #pragma unroll
    for (int i = 0; i < 8; ++i) ef[i] = 0.0f;
    int r = -1, c = -1;
    if (e < E) {
        r = eidx[e];
        c = eidx[E + e];
        const float4 r0 = *(const float4*)(pk + (size_t)r * 8);
        const float4 r1 = *(const float4*)(pk + (size_t)r * 8 + 4);
        const float4 c0 = *(const float4*)(pk + (size_t)c * 8);
        const float4 c1 = *(const float4*)(pk + (size_t)c * 8 + 4);

        const float dx = c0.x - r0.x;
        const float dy = c0.y - r0.y;
        const float dz = c0.z - r0.z;
        const float nrx = r0.w, nry = r1.x, nrz = r1.y;
        const float ncx = c0.w, ncy = c1.x, ncz = c1.y;
        const float ndot = nrx*ncx + nry*ncy + nrz*ncz;
        const float dn = sqrtf(dx*dx + dy*dy + dz*dz) + EPSF;
        const float inv_dn = 1.0f / dn;
        float cr = (nrx*dx + nry*dy + nrz*dz) * inv_dn;
        float cc = (ncx*dx + ncy*dy + ncz*dz) * inv_dn;
        const float lo = -1.0f + EPSF, hi = 1.0f - EPSF;
        cr = fminf(fmaxf(cr, lo), hi);
        cc = fminf(fmaxf(cc, lo), hi);
        ef[0] = dx; ef[1] = dy; ef[2] = dz; ef[3] = ndot;
        ef[4] = cr; ef[5] = cc; ef[6] = c1.z - r1.z; ef[7] = c1.w - r1.w;
    }
    nidbuf[t]       = r;
    nidbuf[256 + t] = c;

    // pack ef -> bf16 LDS row (16B aligned store)
    {
        int p[4];
        #pragma unroll
        for (int i = 0; i < 4; ++i) {
            p[i] = ((unsigned short)f2bf(ef[2*i])) |
                   (((unsigned)(unsigned short)f2bf(ef[2*i+1])) << 16);
        }
        *(int4*)&ef_lds[wv][ln][0] = make_int4(p[0], p[1], p[2], p[3]);
    }

    __syncthreads();  // weights visible to all waves

    // ---- hoist weight fragments into registers (loop-invariant) ----
    short8 fw1[4], fw2[2][2], fw3;
    #pragma unroll
    for (int nt = 0; nt < 4; ++nt)
        fw1[nt] = *(const short8*)&w1t[nt*16 + m][qd*8];
    #pragma unroll
    for (int ks = 0; ks < 2; ++ks)
        #pragma unroll
        for (int nt = 0; nt < 2; ++nt)
            fw2[ks][nt] = *(const short8*)&w2t[nt*16 + m][ks*32 + qd*8];
    fw3 = *(const short8*)&w3t[m][qd*8];

    float bias1[4], bias2[2];
    #pragma unroll
    for (int nt = 0; nt < 4; ++nt) bias1[nt] = b1[nt*16 + m];
    #pragma unroll
    for (int nt = 0; nt < 2; ++nt) bias2[nt] = b2[nt*16 + m];
    const float bias3 = b3[m];

    float ssum = 0.0f, qsum = 0.0f;

    for (int tl = 0; tl < 4; ++tl) {
        // ---- layer 1: A = ef tile (K=8 padded to 32) ----
        short8 a1 = {0,0,0,0,0,0,0,0};
        if (qd == 0) a1 = *(const short8*)&ef_lds[wv][tl*16 + m][0];
        float4v c1[4];
        #pragma unroll
        for (int nt = 0; nt < 4; ++nt) {
            c1[nt] = (float4v){bias1[nt], bias1[nt], bias1[nt], bias1[nt]};
            c1[nt] = __builtin_amdgcn_mfma_f32_16x16x32_bf16(a1, fw1[nt], c1[nt], 0, 0, 0);
        }
        #pragma unroll
        for (int nt = 0; nt < 4; ++nt)
            #pragma unroll
            for (int rg = 0; rg < 4; ++rg)
                h1_lds[wv][qd*4 + rg][nt*16 + m] = f2bf(gelu_fast(c1[nt][rg]));

        // ---- layer 2: K=64 (2 steps), N=32 (2 tiles) ----
        float4v c2[2];
        #pragma unroll
        for (int nt = 0; nt < 2; ++nt)
            c2[nt] = (float4v){bias2[nt], bias2[nt], bias2[nt], bias2[nt]};
        #pragma unroll
        for (int ks = 0; ks < 2; ++ks) {
            const short8 a2 = *(const short8*)&h1_lds[wv][m][ks*32 + qd*8];
            #pragma unroll
            for (int nt = 0; nt < 2; ++nt)
                c2[nt] = __builtin_amdgcn_mfma_f32_16x16x32_bf16(a2, fw2[ks][nt], c2[nt], 0, 0, 0);
        }
        #pragma unroll
        for (int nt = 0; nt < 2; ++nt)
            #pragma unroll
            for (int rg = 0; rg < 4; ++rg)
                h2_lds[wv][qd*4 + rg][nt*16 + m] = f2bf(gelu_fast(c2[nt][rg]));

        // ---- layer 3: K=32, N=16 ----
        const short8 a3 = *(const short8*)&h2_lds[wv][m][qd*8];
        float4v c3 = (float4v){bias3, bias3, bias3, bias3};
        c3 = __builtin_amdgcn_mfma_f32_16x16x32_bf16(a3, fw3, c3, 0, 0, 0);

        // ---- stage h3 (fp16) for marshalled scatter + f32 BN stats ----
        const int ebase = wv*64 + tl*16 + qd*4;
        #pragma unroll
        for (int rg = 0; rg < 4; ++rg) {
            const int ebl = ebase + rg;
            float v = c3[rg];
            hbuf16[ebl][m] = f2h(v);
            if (nidbuf[ebl] < 0) v = 0.0f;    // tail edge: exclude from stats
            ssum += v;
            qsum += v * v;
        }
    }

    // ---- marshalled 9-lane scatter: one 64B line event per endpoint ----
    // wave-local: 64 slots x 2 endpoints = 128 jobs; 7 jobs x 9 lanes / instr.
    {
        const int jid  = ln / 9;          // 0..6 (lane 63 idle)
        const int role = ln - jid * 9;    // 0..8
        #pragma unroll 1
        for (int it = 0; it < 19; ++it) {
            const int j = it * 7 + jid;
            if (jid < 7 && j < 128) {
                const int slot = wv * 64 + (j >> 1);
                const int side = j & 1;
                const int nid  = nidbuf[side * 256 + slot];
                if (nid >= 0) {
                    const unsigned data = (role == 8)
                        ? 0x3C00u                                   // deg += 1.0h
                        : *(const unsigned*)&hbuf16[slot][role * 2];
                    atomic_pk_add_f16(acch + (size_t)nid * 32 + role * 2, data);
                }
            }
        }
    }

    // BN stats: lane holds (feat=m) partial over its 16 edges; reduce quads
    ssum += __shfl_xor(ssum, 16); ssum += __shfl_xor(ssum, 32);
    qsum += __shfl_xor(qsum, 16); qsum += __shfl_xor(qsum, 32);
    if (qd == 0) redbuf[wv][m]      = ssum;
    if (qd == 1) redbuf[wv][16 + m] = qsum;
    __syncthreads();

    if (t < 32) {
        epartial[(size_t)blockIdx.x * 32 + t] =
            redbuf[0][t] + redbuf[1][t] + redbuf[2][t] + redbuf[3][t];
    }
}

// ---------------------------------------------------------------------------
// Sum per-block partials [nblk][32] -> stats[32]. One block per stat index.
// ---------------------------------------------------------------------------
__global__ __launch_bounds__(256) void reduce_partials(
    const float* __restrict__ p, int nblk, float* __restrict__ stats)
{
    const int k = blockIdx.x;
    float s = 0.0f;
    for (int i = threadIdx.x; i < nblk; i += blockDim.x) s += p[(size_t)i * 32 + k];
    #pragma unroll
    for (int o = 32; o > 0; o >>= 1) s += __shfl_xor(s, o);
    __shared__ float w[4];
    if ((threadIdx.x & 63) == 0) w[threadIdx.x >> 6] = s;
    __syncthreads();
    if (threadIdx.x == 0) stats[k] = w[0] + w[1] + w[2] + w[3];
}

// ---------------------------------------------------------------------------
// BN finalize -> affine coefficients: out = a*x + c
// ---------------------------------------------------------------------------
__global__ void finalize_bn(const float* __restrict__ stats,
                            const float* __restrict__ g, const float* __restrict__ b,
                            float cnt_inv, float* __restrict__ coef)
{
    const int j = threadIdx.x;
    if (j < 16) {
        const float mean = stats[j] * cnt_inv;
        const float var  = stats[16 + j] * cnt_inv - mean * mean;
        const float inv  = rsqrtf(var + BN_EPSF);
        const float a    = g[j] * inv;
        coef[j]      = a;
        coef[16 + j] = b[j] - mean * a;
    }
}

// ---------------------------------------------------------------------------
// Node kernel: decode fp16 acc line (feats + deg), edge-BN affine + degree
// norm, 16x16 projection, store y to d_out, block-reduced node-BN partials.
// ---------------------------------------------------------------------------
__global__ __launch_bounds__(256) void node_kernel(
    const unsigned short* __restrict__ acch,
    const float* __restrict__ ecoef,
    const float* __restrict__ Wp, const float* __restrict__ bp,
    float* __restrict__ y, float* __restrict__ npartial, int N)
{
    __shared__ float redbuf[4][32];
    const int t = threadIdx.x;
    const int n = blockIdx.x * 256 + t;

    float yv[16];
    #pragma unroll
    for (int j = 0; j < 16; ++j) yv[j] = 0.0f;

    if (n < N) {
        const unsigned short* row = acch + (size_t)n * 32;
        const uint4 u0 = *(const uint4*)row;
        const uint4 u1 = *(const uint4*)(row + 8);
        const float d  = __half2float(__ushort_as_half(row[16]));
        const float inv = 1.0f / fmaxf(d, 1.0f);
        unsigned w[8] = {u0.x, u0.y, u0.z, u0.w, u1.x, u1.y, u1.z, u1.w};
        float x[16];
        #pragma unroll
        for (int q = 0; q < 8; ++q) {
            x[2*q]   = __half2float(__ushort_as_half((unsigned short)(w[q] & 0xFFFFu)));
            x[2*q+1] = __half2float(__ushort_as_half((unsigned short)(w[q] >> 16)));
        }
        #pragma unroll
        for (int j = 0; j < 16; ++j)
            x[j] = (ecoef[j] * x[j] + ecoef[16 + j] * d) * inv;

        #pragma unroll
        for (int j = 0; j < 16; ++j) yv[j] = bp[j];
        #pragma unroll
        for (int i = 0; i < 16; ++i) {
            const float v = x[i];
            #pragma unroll
            for (int j = 0; j < 16; ++j) yv[j] += v * Wp[i*16 + j];
        }
        float4* yrow = (float4*)(y + (size_t)n * 16);
        #pragma unroll
        for (int q = 0; q < 4; ++q) {
            float4 o;
            o.x = yv[4*q+0]; o.y = yv[4*q+1]; o.z = yv[4*q+2]; o.w = yv[4*q+3];
            yrow[q] = o;
        }
    }

    const int wave = t >> 6;
    #pragma unroll
    for (int j = 0; j < 16; ++j) {
        float s = yv[j];
        float q = yv[j] * yv[j];
        #pragma unroll
        for (int o = 32; o > 0; o >>= 1) {
            s += __shfl_xor(s, o);
            q += __shfl_xor(q, o);
        }
        if ((t & 63) == 0) {
            redbuf[wave][j]      = s;
            redbuf[wave][16 + j] = q;
        }
    }
    __syncthreads();
    if (t < 32) {
        npartial[(size_t)blockIdx.x * 32 + t] =
            redbuf[0][t] + redbuf[1][t] + redbuf[2][t] + redbuf[3][t];
    }
}

// ---------------------------------------------------------------------------
// Epilogue: out = out * a2 + c2 (node BN affine), in place, float4.
// ---------------------------------------------------------------------------
__global__ __launch_bounds__(256) void final_kernel(
    float* __restrict__ out, const float* __restrict__ ncoef, int total)
{
    const int i = (blockIdx.x * blockDim.x + threadIdx.x) * 4;
    if (i < total) {
        const float4 v = *(const float4*)(out + i);
        const int j = i & 15;
        const float4 a = *(const float4*)(ncoef + j);
        const float4 c = *(const float4*)(ncoef + 16 + j);
        float4 o;
        o.x = v.x * a.x + c.x;
        o.y = v.y * a.y + c.y;
        o.z = v.z * a.z + c.z;
        o.w = v.w * a.w + c.w;
        *(float4*)(out + i) = o;
    }
}

extern "C" void kernel_launch(void* const* d_in, const int* in_sizes, int n_in,
                              void* d_out, int out_size, void* d_ws, size_t ws_size,
                              hipStream_t stream) {
    const float* coords = (const float*)d_in[0];
    const float* normals = (const float*)d_in[1];
    const float* curv = (const float*)d_in[2];
    const int*   eidx = (const int*)d_in[3];
    const float* W1 = (const float*)d_in[4];
    const float* b1 = (const float*)d_in[5];
    const float* W2 = (const float*)d_in[6];
    const float* b2 = (const float*)d_in[7];
    const float* W3 = (const float*)d_in[8];
    const float* b3 = (const float*)d_in[9];
    const float* Wp = (const float*)d_in[10];
    const float* bp = (const float*)d_in[11];
    const float* bn_edge_g = (const float*)d_in[12];
    const float* bn_edge_b = (const float*)d_in[13];
    const float* bn_node_g = (const float*)d_in[14];
    const float* bn_node_b = (const float*)d_in[15];

    const int N = in_sizes[0] / 3;
    const int E = in_sizes[3] / 2;

    const int eblocks = (E + 255) / 256;
    const int nblocks = (N + 255) / 256;

    // workspace layout:
    float* ws = (float*)d_ws;
    unsigned short* acch = (unsigned short*)ws;          // N lines x 32 halves (64B)
    float* ecoef    = ws + (size_t)N * 16;               // 32
    float* ncoef    = ecoef + 32;                        // 32
    float* estats   = ncoef + 32;                        // 32
    float* nstats   = estats + 32;                       // 32
    float* epartial = nstats + 32;                       // eblocks*32
    float* npartial = epartial + (size_t)eblocks * 32;   // nblocks*32
    float* pk       = npartial + (size_t)nblocks * 32;   // N*8

    pack_nodes_zero<<<nblocks, 256, 0, stream>>>(coords, normals, curv, pk, acch, N);

    edge_kernel<<<eblocks, 256, 0, stream>>>(
        pk, eidx, W1, b1, W2, b2, W3, b3, acch, epartial, E);

    reduce_partials<<<32, 256, 0, stream>>>(epartial, eblocks, estats);
    finalize_bn<<<1, 64, 0, stream>>>(estats, bn_edge_g, bn_edge_b, 1.0f / (float)E, ecoef);

    node_kernel<<<nblocks, 256, 0, stream>>>(
        acch, ecoef, Wp, bp, (float*)d_out, npartial, N);

    reduce_partials<<<32, 256, 0, stream>>>(npartial, nblocks, nstats);
    finalize_bn<<<1, 64, 0, stream>>>(nstats, bn_node_g, bn_node_b, 1.0f / (float)N, ncoef);

    const int total = N * 16;
    final_kernel<<<(total / 4 + 255) / 256, 256, 0, stream>>>((float*)d_out, ncoef, total);
}